// Round 1
// baseline (58273.138 us; speedup 1.0000x reference)
//
#include <hip/hip_runtime.h>

// ----------------------------------------------------------------------------
// 2-layer LayerNorm-LSTM, SEQ=1024, B=64, IN=256, H=512.
// Persistent pipelined kernel: 64 WGs layer0-matmul + 64 WGs layer1-matmul
// (weights LDS-resident, bf16 MFMA 16x16x32) + 64 WGs elementwise/LN (one per
// batch row, cell state in registers). Producer-consumer flag sync, no grid
// barrier. Layer1 runs one step behind layer0.
// ----------------------------------------------------------------------------

typedef short  s16x8 __attribute__((ext_vector_type(8)));
typedef float  f32x4 __attribute__((ext_vector_type(4)));
typedef unsigned short u16;
typedef unsigned int   u32;

constexpr int kSeq = 1024;
constexpr int kB   = 64;
constexpr int kIn  = 256;
constexpr int kH   = 512;
constexpr int kG   = 2048;   // 4*H
#define LN_EPS 1e-5f

// ws layout (bytes); all sizes multiples of 256
constexpr size_t OF_FLAGS = 0;                                   // 1024 B: 4 arrays of 64 u32
constexpr size_t OF_HA    = 1024;                                // 2*B*H bf16 (double buffered)
constexpr size_t OF_HB    = OF_HA  + (size_t)2*kB*kH*2;
constexpr size_t OF_G0P   = OF_HB  + (size_t)2*kB*kH*2;          // [2 ks][B][4H] f32 partials
constexpr size_t OF_G1P   = OF_G0P + (size_t)2*kB*kG*4;
constexpr size_t OF_W0    = OF_G1P + (size_t)2*kB*kG*4;          // 2048*768 bf16, MFMA-swizzled
constexpr size_t OF_W1    = OF_W0  + (size_t)kG*768*2;           // 2048*1024 bf16, swizzled
constexpr size_t OF_XBF   = OF_W1  + (size_t)kG*1024*2;          // SEQ*B*IN bf16
constexpr size_t WS_NEED  = OF_XBF + (size_t)kSeq*kB*kIn*2;

constexpr size_t OUT_HFIN = (size_t)kSeq*kB*kH;                  // outputs | h_final | c_final
constexpr size_t OUT_CFIN = OUT_HFIN + (size_t)2*kB*kH;

__device__ __forceinline__ u16 f2bf(float f) {
  u32 u = __float_as_uint(f);
  return (u16)((u + 0x7fffu + ((u >> 16) & 1u)) >> 16);  // RNE; inputs are finite
}

// Spin until all 64 flags[l] >= target. Called by threads 0..63 only.
__device__ __forceinline__ void wait_flags_ge(u32* f, u32 target) {
  const int l = threadIdx.x;
  while (true) {
    u32 v = __hip_atomic_load(&f[l], __ATOMIC_RELAXED, __HIP_MEMORY_SCOPE_AGENT);
    if (__all((int)(v >= target))) break;
    __builtin_amdgcn_s_sleep(1);
  }
}

// ---------------------------------------------------------------- conversions
__global__ void conv_x_k(const float* __restrict__ x, u16* __restrict__ xd, size_t n) {
  size_t i = (size_t)blockIdx.x * blockDim.x + threadIdx.x;
  size_t st = (size_t)gridDim.x * blockDim.x;
  for (; i < n; i += st) xd[i] = f2bf(x[i]);
}

// W0 [2048][768] -> per-WG chunks [ns(32)][kstL(24)][nt(4)][lane(64)][8]
// kstL<16: ks=0 (K cols 0..511 = x + hA[0:256]); kstL>=16: ks=1 (cols 512..767)
__global__ void conv_w0_k(const float* __restrict__ W, u16* __restrict__ Wd) {
  int i = blockIdx.x * blockDim.x + threadIdx.x;
  if (i >= 32 * 24 * 4 * 64 * 8) return;
  int j = i & 7, l = (i >> 3) & 63, nt = (i >> 9) & 3;
  int r = i >> 11;                 // ns*24 + kstL
  int kstL = r % 24, ns = r / 24;
  int ks = (kstL >= 16) ? 1 : 0;
  int kst = ks ? (kstL - 16) : kstL;
  int n = ns * 64 + nt * 16 + (l & 15);
  int k = (ks ? 512 : 0) + kst * 32 + ((l >> 4) << 3) + j;
  Wd[i] = f2bf(W[(size_t)n * 768 + k]);
}

// W1 [2048][1024] cols = [hA(512)|hB(512)], virtual K order per (ks):
// ks*512 + kst*32+... ; seg0=hA[0:256] seg1=hB[0:256] seg2=hA[256:512] seg3=hB[256:512]
__global__ void conv_w1_k(const float* __restrict__ W, u16* __restrict__ Wd) {
  int i = blockIdx.x * blockDim.x + threadIdx.x;
  if (i >= 32 * 2 * 16 * 4 * 64 * 8) return;
  int j = i & 7, l = (i >> 3) & 63, nt = (i >> 9) & 3;
  int r = i >> 11;                 // (ns*2+ks)*16 + kst
  int kst = r & 15; int sk = r >> 4;
  int ks = sk & 1, ns = sk >> 1;
  int kv = ks * 512 + kst * 32 + ((l >> 4) << 3) + j;
  int seg = kv >> 8, q = kv & 255;
  int col = (seg == 0) ? q : (seg == 1) ? 512 + q : (seg == 2) ? 256 + q : 768 + q;
  int n = ns * 64 + nt * 16 + (l & 15);
  Wd[i] = f2bf(W[(size_t)n * 1024 + col]);
}

__global__ void init_k(u32* flags, u16* hA, u16* hB, const float* __restrict__ h0) {
  int i = blockIdx.x * blockDim.x + threadIdx.x;   // 0..32767
  if (i < 256) flags[i] = 0;
  hA[(size_t)kB * kH + i] = f2bf(h0[i]);                       // hA parity-1 = h0[layer0]
  hB[(size_t)kB * kH + i] = f2bf(h0[(size_t)kB * kH + i]);     // hB parity-1 = h0[layer1]
}

// ---------------------------------------------------------------- elementwise
struct EwConst {
  float bi0, bf0, bo0, bc0, bi1, bf1, bo1, bc1;
  float ga0, ga1, be0, be1;
};

__device__ __forceinline__ void ew_cell(
    const float* __restrict__ gpart, const EwConst& C,
    float& cr0, float& cr1, int b, int tid,
    u16* __restrict__ hdst, float* __restrict__ fout,
    float* __restrict__ finh, float* __restrict__ finc, float* red)
{
  const int j0 = tid, j1 = tid + 256;
  const float* p0 = gpart + (size_t)b * kG;
  const float* p1 = gpart + (size_t)kB * kG + (size_t)b * kG;
  const float gi0 = p0[j0]          + p1[j0]          + C.bi0;
  const float gf0 = p0[kH + j0]     + p1[kH + j0]     + C.bf0;
  const float go0 = p0[2 * kH + j0] + p1[2 * kH + j0] + C.bo0;
  const float gc0 = p0[3 * kH + j0] + p1[3 * kH + j0] + C.bc0;
  const float gi1 = p0[j1]          + p1[j1]          + C.bi1;
  const float gf1 = p0[kH + j1]     + p1[kH + j1]     + C.bf1;
  const float go1 = p0[2 * kH + j1] + p1[2 * kH + j1] + C.bo1;
  const float gc1 = p0[3 * kH + j1] + p1[3 * kH + j1] + C.bc1;
  const float i0 = 1.f / (1.f + __expf(-gi0));
  const float f0 = 1.f / (1.f + __expf(-gf0));
  const float o0 = 1.f / (1.f + __expf(-go0));
  const float d0 = tanhf(gc0);
  const float i1 = 1.f / (1.f + __expf(-gi1));
  const float f1 = 1.f / (1.f + __expf(-gf1));
  const float o1 = 1.f / (1.f + __expf(-go1));
  const float d1 = tanhf(gc1);
  const float cn0 = i0 * d0 + f0 * cr0;
  const float cn1 = i1 * d1 + f1 * cr1;
  cr0 = cn0; cr1 = cn1;
  float s = cn0 + cn1, q = cn0 * cn0 + cn1 * cn1;
  #pragma unroll
  for (int m = 32; m > 0; m >>= 1) { s += __shfl_xor(s, m); q += __shfl_xor(q, m); }
  if ((tid & 63) == 0) { red[tid >> 6] = s; red[4 + (tid >> 6)] = q; }
  __syncthreads();
  const float mu = (red[0] + red[1] + red[2] + red[3]) * (1.f / 512.f);
  const float ms = (red[4] + red[5] + red[6] + red[7]) * (1.f / 512.f);
  __syncthreads();
  const float rstd = rsqrtf(ms - mu * mu + LN_EPS);
  const float h0 = o0 * tanhf((cn0 - mu) * rstd * C.ga0 + C.be0);
  const float h1 = o1 * tanhf((cn1 - mu) * rstd * C.ga1 + C.be1);
  hdst[j0] = f2bf(h0); hdst[j1] = f2bf(h1);
  if (fout) { fout[j0] = h0; fout[j1] = h1; }
  if (finh) { finh[j0] = h0; finh[j1] = h1; finc[j0] = cn0; finc[j1] = cn1; }
}

// ---------------------------------------------------------------- persistent
__global__ __launch_bounds__(256, 1) void lstm_persist(
    const u16* __restrict__ xbf, const u16* __restrict__ w0s, const u16* __restrict__ w1s,
    u16* __restrict__ hA, u16* __restrict__ hB,
    float* __restrict__ g0p, float* __restrict__ g1p, u32* flags,
    const float* __restrict__ b0, const float* __restrict__ lg0, const float* __restrict__ lb0,
    const float* __restrict__ b1, const float* __restrict__ lg1, const float* __restrict__ lb1,
    const float* __restrict__ c0in, float* __restrict__ out)
{
  extern __shared__ char smem_raw[];
  const int bid = blockIdx.x, tid = threadIdx.x;
  u32* g0f = flags;
  u32* g1f = flags + 64;
  u32* hAf = flags + 128;
  u32* hBf = flags + 192;

  if (bid < 128) {
    // ------------- matmul roles: bid<64 layer0, else layer1 -------------
    s16x8* wlds = (s16x8*)smem_raw;
    const bool isA = (bid < 64);
    const int sub = isA ? bid : bid - 64;
    const int ns = sub >> 1, ks = sub & 1;
    const int KST = isA ? (ks ? 8 : 16) : 16;
    const s16x8* wsrc = isA
        ? (const s16x8*)w0s + (size_t)ns * (24 * 256) + (size_t)ks * (16 * 256)
        : (const s16x8*)w1s + (size_t)sub * (16 * 256);
    for (int i = tid; i < KST * 256; i += 256) wlds[i] = wsrc[i];
    __syncthreads();

    const int lane = tid & 63, wid = tid >> 6;
    const int brow = wid * 16 + (lane & 15);
    const int klane = (lane >> 4) << 3;
    const int nbase = ns * 64;
    u32* myflag = (isA ? g0f : g1f) + sub;
    float* gp = (isA ? g0p : g1p) + (size_t)ks * (kB * kG);

    for (int t = 0; t < kSeq; ++t) {
      f32x4 zero = {0.f, 0.f, 0.f, 0.f};
      f32x4 acc[4];
      #pragma unroll
      for (int nt = 0; nt < 4; ++nt) acc[nt] = zero;

      auto mm4 = [&](s16x8 a, int kst) {
        #pragma unroll
        for (int nt = 0; nt < 4; ++nt)
          acc[nt] = __builtin_amdgcn_mfma_f32_16x16x32_bf16(
              a, wlds[(kst * 4 + nt) * 64 + lane], acc[nt], 0, 0, 0);
      };

      if (isA) {
        s16x8 xpre[8];
        if (ks == 0) {   // prefetch x fragments before the flag wait (x is static)
          const u16* xrow = xbf + ((size_t)t * kB + brow) * kIn + klane;
          #pragma unroll
          for (int kk = 0; kk < 8; ++kk) xpre[kk] = *(const s16x8*)(xrow + kk * 32);
        }
        if (t > 0) { if (tid < 64) wait_flags_ge(hAf, (u32)t); }
        __syncthreads();
        __threadfence();
        const u16* hrow = hA + (size_t)((t + 1) & 1) * kB * kH + (size_t)brow * kH + klane;
        if (ks == 0) {
          for (int kk = 0; kk < 8; ++kk)  mm4(xpre[kk], kk);
          for (int kk = 8; kk < 16; ++kk) mm4(*(const s16x8*)(hrow + (kk - 8) * 32), kk);
        } else {
          for (int kk = 0; kk < 8; ++kk)  mm4(*(const s16x8*)(hrow + 256 + kk * 32), kk);
        }
      } else {
        // layer1: consume hB(t-1) first (flag is one tick old -> usually no wait)
        if (t > 0) { if (tid < 64) wait_flags_ge(hBf, (u32)t); }
        __syncthreads();
        __threadfence();
        const u16* hbrow = hB + (size_t)((t + 1) & 1) * kB * kH + (size_t)brow * kH + klane + ks * 256;
        for (int kk = 8; kk < 16; ++kk) mm4(*(const s16x8*)(hbrow + (kk - 8) * 32), kk);
        if (tid < 64) wait_flags_ge(hAf, (u32)(t + 1));
        __syncthreads();
        __threadfence();
        const u16* harow = hA + (size_t)(t & 1) * kB * kH + (size_t)brow * kH + klane + ks * 256;
        for (int kk = 0; kk < 8; ++kk)  mm4(*(const s16x8*)(harow + kk * 32), kk);
      }

      // partial-gate store: D layout col=lane&15, row=(lane>>4)*4+r  [m89]
      #pragma unroll
      for (int nt = 0; nt < 4; ++nt) {
        const int n = nbase + nt * 16 + (lane & 15);
        #pragma unroll
        for (int r = 0; r < 4; ++r) {
          const int bo = wid * 16 + ((lane >> 4) << 2) + r;
          gp[(size_t)bo * kG + n] = acc[nt][r];
        }
      }
      __threadfence();
      __syncthreads();
      if (tid == 0)
        __hip_atomic_store(myflag, (u32)(t + 1), __ATOMIC_RELAXED, __HIP_MEMORY_SCOPE_AGENT);
    }
  } else {
    // ------------- elementwise + LN role, one WG per batch row -------------
    float* red = (float*)smem_raw;
    const int b = bid - 128;
    const int j0 = tid, j1 = tid + 256;
    float ca0 = c0in[(size_t)b * kH + j0], ca1 = c0in[(size_t)b * kH + j1];
    float cb0 = c0in[(size_t)kB * kH + (size_t)b * kH + j0];
    float cb1 = c0in[(size_t)kB * kH + (size_t)b * kH + j1];

    EwConst K0, K1;
    K0.bi0 = b0[j0]; K0.bf0 = b0[kH + j0]; K0.bo0 = b0[2 * kH + j0]; K0.bc0 = b0[3 * kH + j0];
    K0.bi1 = b0[j1]; K0.bf1 = b0[kH + j1]; K0.bo1 = b0[2 * kH + j1]; K0.bc1 = b0[3 * kH + j1];
    K0.ga0 = lg0[j0]; K0.ga1 = lg0[j1]; K0.be0 = lb0[j0]; K0.be1 = lb0[j1];
    K1.bi0 = b1[j0]; K1.bf0 = b1[kH + j0]; K1.bo0 = b1[2 * kH + j0]; K1.bc0 = b1[3 * kH + j0];
    K1.bi1 = b1[j1]; K1.bf1 = b1[kH + j1]; K1.bo1 = b1[2 * kH + j1]; K1.bc1 = b1[3 * kH + j1];
    K1.ga0 = lg1[j0]; K1.ga1 = lg1[j1]; K1.be0 = lb1[j0]; K1.be1 = lb1[j1];

    for (int tau = 0; tau <= kSeq; ++tau) {
      if (tau < kSeq) {             // layer0, step tau
        if (tid < 64) wait_flags_ge(g0f, (u32)(tau + 1));
        __syncthreads();
        __threadfence();
        const bool last = (tau == kSeq - 1);
        ew_cell(g0p, K0, ca0, ca1, b, tid,
                hA + (size_t)(tau & 1) * kB * kH + (size_t)b * kH,
                nullptr,
                last ? out + OUT_HFIN + (size_t)b * kH : nullptr,
                last ? out + OUT_CFIN + (size_t)b * kH : nullptr, red);
        __threadfence();
        __syncthreads();
        if (tid == 0)
          __hip_atomic_store(hAf + b, (u32)(tau + 1), __ATOMIC_RELAXED, __HIP_MEMORY_SCOPE_AGENT);
      }
      if (tau >= 1) {               // layer1, step tau-1
        const int t = tau - 1;
        if (tid < 64) wait_flags_ge(g1f, (u32)(t + 1));
        __syncthreads();
        __threadfence();
        const bool last = (t == kSeq - 1);
        ew_cell(g1p, K1, cb0, cb1, b, tid,
                hB + (size_t)(t & 1) * kB * kH + (size_t)b * kH,
                out + ((size_t)t * kB + b) * kH,
                last ? out + OUT_HFIN + (size_t)kB * kH + (size_t)b * kH : nullptr,
                last ? out + OUT_CFIN + (size_t)kB * kH + (size_t)b * kH : nullptr, red);
        __threadfence();
        __syncthreads();
        if (tid == 0)
          __hip_atomic_store(hBf + b, (u32)(t + 1), __ATOMIC_RELAXED, __HIP_MEMORY_SCOPE_AGENT);
      }
    }
  }
}

// ---------------------------------------------------------------- launch
extern "C" void kernel_launch(void* const* d_in, const int* in_sizes, int n_in,
                              void* d_out, int out_size, void* d_ws, size_t ws_size,
                              hipStream_t stream) {
  (void)in_sizes; (void)n_in; (void)out_size;
  const float* x   = (const float*)d_in[0];
  const float* h0  = (const float*)d_in[1];
  const float* c0  = (const float*)d_in[2];
  const float* W0  = (const float*)d_in[3];
  const float* b0  = (const float*)d_in[4];
  const float* g0  = (const float*)d_in[5];
  const float* be0 = (const float*)d_in[6];
  const float* W1  = (const float*)d_in[7];
  const float* b1  = (const float*)d_in[8];
  const float* g1  = (const float*)d_in[9];
  const float* be1 = (const float*)d_in[10];
  float* out = (float*)d_out;

  if (ws_size < WS_NEED) return;   // fail loudly (output stays poisoned)

  char* w = (char*)d_ws;
  u32* flags = (u32*)(w + OF_FLAGS);
  u16* hA    = (u16*)(w + OF_HA);
  u16* hB    = (u16*)(w + OF_HB);
  float* g0p = (float*)(w + OF_G0P);
  float* g1p = (float*)(w + OF_G1P);
  u16* w0s   = (u16*)(w + OF_W0);
  u16* w1s   = (u16*)(w + OF_W1);
  u16* xbf   = (u16*)(w + OF_XBF);

  hipLaunchKernelGGL(conv_x_k,  dim3(2048), dim3(256), 0, stream, x, xbf, (size_t)kSeq * kB * kIn);
  hipLaunchKernelGGL(conv_w0_k, dim3(6144), dim3(256), 0, stream, W0, w0s);
  hipLaunchKernelGGL(conv_w1_k, dim3(8192), dim3(256), 0, stream, W1, w1s);
  hipLaunchKernelGGL(init_k,    dim3(128),  dim3(256), 0, stream, flags, hA, hB, h0);
  hipLaunchKernelGGL(lstm_persist, dim3(192), dim3(256), 65536, stream,
                     xbf, w0s, w1s, hA, hB, g0p, g1p, flags,
                     b0, g0, be0, b1, g1, be1, c0, out);
}

// Round 2
// 17688.298 us; speedup vs baseline: 3.2944x; 3.2944x over previous
//
#include <hip/hip_runtime.h>

// ----------------------------------------------------------------------------
// 2-layer LayerNorm-LSTM, SEQ=1024, B=64, IN=256, H=512.
// Persistent pipelined kernel: 64 WGs layer0-matmul + 64 WGs layer1-matmul
// (weights LDS-resident, bf16 MFMA 16x16x32) + 64 WGs elementwise/LN (one per
// batch row, cell state in registers). Producer-consumer flag sync, no grid
// barrier, NO __threadfence (full L2 wb/inv on gfx950!). All cross-WG data
// moves via sc0/sc1 coherent accesses (relaxed agent-scope atomics); release
// ordering = s_waitcnt vmcnt(0) + barrier + relaxed flag store.
// ----------------------------------------------------------------------------

typedef short  s16x8 __attribute__((ext_vector_type(8)));
typedef float  f32x4 __attribute__((ext_vector_type(4)));
typedef unsigned short u16;
typedef unsigned int   u32;
typedef unsigned long long u64;

constexpr int kSeq = 1024;
constexpr int kB   = 64;
constexpr int kIn  = 256;
constexpr int kH   = 512;
constexpr int kG   = 2048;   // 4*H
#define LN_EPS 1e-5f

// ws layout (bytes); all sizes multiples of 256
constexpr size_t OF_FLAGS = 0;                                   // 1024 B: 4 arrays of 64 u32
constexpr size_t OF_HA    = 1024;                                // 2*B*H bf16 (double buffered)
constexpr size_t OF_HB    = OF_HA  + (size_t)2*kB*kH*2;
constexpr size_t OF_G0P   = OF_HB  + (size_t)2*kB*kH*2;          // [2 ks][B][4H] f32 partials
constexpr size_t OF_G1P   = OF_G0P + (size_t)2*kB*kG*4;
constexpr size_t OF_W0    = OF_G1P + (size_t)2*kB*kG*4;          // 2048*768 bf16, MFMA-swizzled
constexpr size_t OF_W1    = OF_W0  + (size_t)kG*768*2;           // 2048*1024 bf16, swizzled
constexpr size_t OF_XBF   = OF_W1  + (size_t)kG*1024*2;          // SEQ*B*IN bf16
constexpr size_t WS_NEED  = OF_XBF + (size_t)kSeq*kB*kIn*2;

constexpr size_t OUT_HFIN = (size_t)kSeq*kB*kH;                  // outputs | h_final | c_final
constexpr size_t OUT_CFIN = OUT_HFIN + (size_t)2*kB*kH;

__device__ __forceinline__ u16 f2bf(float f) {
  u32 u = __float_as_uint(f);
  return (u16)((u + 0x7fffu + ((u >> 16) & 1u)) >> 16);  // RNE; inputs are finite
}

// ---- coherent (sc0 sc1, LLC point-of-coherence) access helpers -------------
__device__ __forceinline__ float load_coh_f32(const float* p) {
  return __hip_atomic_load(p, __ATOMIC_RELAXED, __HIP_MEMORY_SCOPE_AGENT);
}
__device__ __forceinline__ float2 load_coh_f32x2(const float* p) {
  u64 v = __hip_atomic_load(reinterpret_cast<const u64*>(p),
                            __ATOMIC_RELAXED, __HIP_MEMORY_SCOPE_AGENT);
  union { u64 u; float2 f; } c; c.u = v; return c.f;
}
__device__ __forceinline__ void store_coh_f32(float* p, float v) {
  __hip_atomic_store(p, v, __ATOMIC_RELAXED, __HIP_MEMORY_SCOPE_AGENT);
}
__device__ __forceinline__ u32 load_coh_u32(const u16* p) {
  return __hip_atomic_load(reinterpret_cast<const u32*>(p),
                           __ATOMIC_RELAXED, __HIP_MEMORY_SCOPE_AGENT);
}
__device__ __forceinline__ void store_coh_u32(u16* p, u32 v) {
  __hip_atomic_store(reinterpret_cast<u32*>(p), v,
                     __ATOMIC_RELAXED, __HIP_MEMORY_SCOPE_AGENT);
}
__device__ __forceinline__ s16x8 load_h_frag(const u16* p) {
  union { u32 u[4]; s16x8 s; } c;
  c.u[0] = load_coh_u32(p);     c.u[1] = load_coh_u32(p + 2);
  c.u[2] = load_coh_u32(p + 4); c.u[3] = load_coh_u32(p + 6);
  return c.s;
}
// per-wave release drain: all prior vmem stores reached the coherence point
__device__ __forceinline__ void drain_vm() {
  asm volatile("s_waitcnt vmcnt(0)" ::: "memory");
}

// Spin until all 64 flags[l] >= target. Called by threads 0..63 only.
__device__ __forceinline__ void wait_flags_ge(u32* f, u32 target) {
  const int l = threadIdx.x;
  while (true) {
    u32 v = __hip_atomic_load(&f[l], __ATOMIC_RELAXED, __HIP_MEMORY_SCOPE_AGENT);
    if (__all((int)(v >= target))) break;
    __builtin_amdgcn_s_sleep(1);
  }
}

// ---------------------------------------------------------------- conversions
__global__ void conv_x_k(const float* __restrict__ x, u16* __restrict__ xd, size_t n) {
  size_t i = (size_t)blockIdx.x * blockDim.x + threadIdx.x;
  size_t st = (size_t)gridDim.x * blockDim.x;
  for (; i < n; i += st) xd[i] = f2bf(x[i]);
}

// W0 [2048][768] -> per-WG chunks [ns(32)][kstL(24)][nt(4)][lane(64)][8]
// kstL<16: ks=0 (K cols 0..511 = x + hA[0:256]); kstL>=16: ks=1 (cols 512..767)
__global__ void conv_w0_k(const float* __restrict__ W, u16* __restrict__ Wd) {
  int i = blockIdx.x * blockDim.x + threadIdx.x;
  if (i >= 32 * 24 * 4 * 64 * 8) return;
  int j = i & 7, l = (i >> 3) & 63, nt = (i >> 9) & 3;
  int r = i >> 11;                 // ns*24 + kstL
  int kstL = r % 24, ns = r / 24;
  int ks = (kstL >= 16) ? 1 : 0;
  int kst = ks ? (kstL - 16) : kstL;
  int n = ns * 64 + nt * 16 + (l & 15);
  int k = (ks ? 512 : 0) + kst * 32 + ((l >> 4) << 3) + j;
  Wd[i] = f2bf(W[(size_t)n * 768 + k]);
}

// W1 [2048][1024] cols = [hA(512)|hB(512)], virtual K order per (ks):
// ks*512 + kst*32+... ; seg0=hA[0:256] seg1=hB[0:256] seg2=hA[256:512] seg3=hB[256:512]
__global__ void conv_w1_k(const float* __restrict__ W, u16* __restrict__ Wd) {
  int i = blockIdx.x * blockDim.x + threadIdx.x;
  if (i >= 32 * 2 * 16 * 4 * 64 * 8) return;
  int j = i & 7, l = (i >> 3) & 63, nt = (i >> 9) & 3;
  int r = i >> 11;                 // (ns*2+ks)*16 + kst
  int kst = r & 15; int sk = r >> 4;
  int ks = sk & 1, ns = sk >> 1;
  int kv = ks * 512 + kst * 32 + ((l >> 4) << 3) + j;
  int seg = kv >> 8, q = kv & 255;
  int col = (seg == 0) ? q : (seg == 1) ? 512 + q : (seg == 2) ? 256 + q : 768 + q;
  int n = ns * 64 + nt * 16 + (l & 15);
  Wd[i] = f2bf(W[(size_t)n * 1024 + col]);
}

__global__ void init_k(u32* flags, u16* hA, u16* hB, const float* __restrict__ h0) {
  int i = blockIdx.x * blockDim.x + threadIdx.x;   // 0..32767
  if (i < 256) flags[i] = 0;
  hA[(size_t)kB * kH + i] = f2bf(h0[i]);                       // hA parity-1 = h0[layer0]
  hB[(size_t)kB * kH + i] = f2bf(h0[(size_t)kB * kH + i]);     // hB parity-1 = h0[layer1]
}

// ---------------------------------------------------------------- elementwise
struct EwConst {
  float bi0, bf0, bo0, bc0, bi1, bf1, bo1, bc1;
  float ga0, ga1, be0, be1;
};

// thread t handles adjacent elements j0=2t, j1=2t+1 (u32-packable h store)
__device__ __forceinline__ void ew_cell(
    const float* __restrict__ gpart, const EwConst& C,
    float& cr0, float& cr1, int b, int tid,
    u16* __restrict__ hdst, float* __restrict__ fout,
    float* __restrict__ finh, float* __restrict__ finc, float* red)
{
  const int j0 = tid * 2;
  const float* p0 = gpart + (size_t)b * kG;
  const float* p1 = gpart + (size_t)kB * kG + (size_t)b * kG;
  float2 a, bb;
  a = load_coh_f32x2(p0 + j0);           bb = load_coh_f32x2(p1 + j0);
  const float gi0 = a.x + bb.x + C.bi0, gi1 = a.y + bb.y + C.bi1;
  a = load_coh_f32x2(p0 + kH + j0);      bb = load_coh_f32x2(p1 + kH + j0);
  const float gf0 = a.x + bb.x + C.bf0, gf1 = a.y + bb.y + C.bf1;
  a = load_coh_f32x2(p0 + 2 * kH + j0);  bb = load_coh_f32x2(p1 + 2 * kH + j0);
  const float go0 = a.x + bb.x + C.bo0, go1 = a.y + bb.y + C.bo1;
  a = load_coh_f32x2(p0 + 3 * kH + j0);  bb = load_coh_f32x2(p1 + 3 * kH + j0);
  const float gc0 = a.x + bb.x + C.bc0, gc1 = a.y + bb.y + C.bc1;

  const float i0 = 1.f / (1.f + __expf(-gi0));
  const float f0 = 1.f / (1.f + __expf(-gf0));
  const float o0 = 1.f / (1.f + __expf(-go0));
  const float d0 = tanhf(gc0);
  const float i1 = 1.f / (1.f + __expf(-gi1));
  const float f1 = 1.f / (1.f + __expf(-gf1));
  const float o1 = 1.f / (1.f + __expf(-go1));
  const float d1 = tanhf(gc1);
  const float cn0 = i0 * d0 + f0 * cr0;
  const float cn1 = i1 * d1 + f1 * cr1;
  cr0 = cn0; cr1 = cn1;
  float s = cn0 + cn1, q = cn0 * cn0 + cn1 * cn1;
  #pragma unroll
  for (int m = 32; m > 0; m >>= 1) { s += __shfl_xor(s, m); q += __shfl_xor(q, m); }
  if ((tid & 63) == 0) { red[tid >> 6] = s; red[4 + (tid >> 6)] = q; }
  __syncthreads();
  const float mu = (red[0] + red[1] + red[2] + red[3]) * (1.f / 512.f);
  const float ms = (red[4] + red[5] + red[6] + red[7]) * (1.f / 512.f);
  __syncthreads();
  const float rstd = rsqrtf(ms - mu * mu + LN_EPS);
  const float hv0 = o0 * tanhf((cn0 - mu) * rstd * C.ga0 + C.be0);
  const float hv1 = o1 * tanhf((cn1 - mu) * rstd * C.ga1 + C.be1);
  store_coh_u32(hdst + j0, ((u32)f2bf(hv1) << 16) | (u32)f2bf(hv0));
  if (fout) { fout[j0] = hv0; fout[j0 + 1] = hv1; }
  if (finh) { finh[j0] = hv0; finh[j0 + 1] = hv1; finc[j0] = cn0; finc[j0 + 1] = cn1; }
}

// ---------------------------------------------------------------- persistent
__global__ __launch_bounds__(256, 1) void lstm_persist(
    const u16* __restrict__ xbf, const u16* __restrict__ w0s, const u16* __restrict__ w1s,
    u16* __restrict__ hA, u16* __restrict__ hB,
    float* __restrict__ g0p, float* __restrict__ g1p, u32* flags,
    const float* __restrict__ b0, const float* __restrict__ lg0, const float* __restrict__ lb0,
    const float* __restrict__ b1, const float* __restrict__ lg1, const float* __restrict__ lb1,
    const float* __restrict__ c0in, float* __restrict__ out)
{
  extern __shared__ char smem_raw[];
  const int bid = blockIdx.x, tid = threadIdx.x;
  u32* g0f = flags;
  u32* g1f = flags + 64;
  u32* hAf = flags + 128;
  u32* hBf = flags + 192;

  if (bid < 128) {
    // ------------- matmul roles: bid<64 layer0, else layer1 -------------
    s16x8* wlds = (s16x8*)smem_raw;
    const bool isA = (bid < 64);
    const int sub = isA ? bid : bid - 64;
    const int ns = sub >> 1, ks = sub & 1;
    const int KST = isA ? (ks ? 8 : 16) : 16;
    const s16x8* wsrc = isA
        ? (const s16x8*)w0s + (size_t)ns * (24 * 256) + (size_t)ks * (16 * 256)
        : (const s16x8*)w1s + (size_t)sub * (16 * 256);
    for (int i = tid; i < KST * 256; i += 256) wlds[i] = wsrc[i];
    __syncthreads();

    const int lane = tid & 63, wid = tid >> 6;
    const int brow = wid * 16 + (lane & 15);
    const int klane = (lane >> 4) << 3;
    const int nbase = ns * 64;
    u32* myflag = (isA ? g0f : g1f) + sub;
    float* gp = (isA ? g0p : g1p) + (size_t)ks * (kB * kG);

    for (int t = 0; t < kSeq; ++t) {
      f32x4 zero = {0.f, 0.f, 0.f, 0.f};
      f32x4 acc[4];
      #pragma unroll
      for (int nt = 0; nt < 4; ++nt) acc[nt] = zero;

      auto mm4 = [&](s16x8 a, int kst) {
        #pragma unroll
        for (int nt = 0; nt < 4; ++nt)
          acc[nt] = __builtin_amdgcn_mfma_f32_16x16x32_bf16(
              a, wlds[(kst * 4 + nt) * 64 + lane], acc[nt], 0, 0, 0);
      };

      if (isA) {
        s16x8 xpre[8];
        if (ks == 0) {   // prefetch x fragments before the flag wait (x is static)
          const u16* xrow = xbf + ((size_t)t * kB + brow) * kIn + klane;
          #pragma unroll
          for (int kk = 0; kk < 8; ++kk) xpre[kk] = *(const s16x8*)(xrow + kk * 32);
        }
        if (t > 0) { if (tid < 64) wait_flags_ge(hAf, (u32)t); }
        __syncthreads();
        const u16* hrow = hA + (size_t)((t + 1) & 1) * kB * kH + (size_t)brow * kH + klane;
        if (ks == 0) {
          for (int kk = 0; kk < 8; ++kk)  mm4(xpre[kk], kk);
          for (int kk = 8; kk < 16; ++kk) mm4(load_h_frag(hrow + (kk - 8) * 32), kk);
        } else {
          for (int kk = 0; kk < 8; ++kk)  mm4(load_h_frag(hrow + 256 + kk * 32), kk);
        }
      } else {
        // layer1: consume hB(t-1) first (flag is one tick old -> usually no wait)
        if (t > 0) { if (tid < 64) wait_flags_ge(hBf, (u32)t); }
        __syncthreads();
        const u16* hbrow = hB + (size_t)((t + 1) & 1) * kB * kH + (size_t)brow * kH + klane + ks * 256;
        for (int kk = 8; kk < 16; ++kk) mm4(load_h_frag(hbrow + (kk - 8) * 32), kk);
        if (tid < 64) wait_flags_ge(hAf, (u32)(t + 1));
        __syncthreads();
        const u16* harow = hA + (size_t)(t & 1) * kB * kH + (size_t)brow * kH + klane + ks * 256;
        for (int kk = 0; kk < 8; ++kk)  mm4(load_h_frag(harow + kk * 32), kk);
      }

      // partial-gate store: D layout col=lane&15, row=(lane>>4)*4+r  [m89]
      #pragma unroll
      for (int nt = 0; nt < 4; ++nt) {
        const int n = nbase + nt * 16 + (lane & 15);
        #pragma unroll
        for (int r = 0; r < 4; ++r) {
          const int bo = wid * 16 + ((lane >> 4) << 2) + r;
          store_coh_f32(&gp[(size_t)bo * kG + n], acc[nt][r]);
        }
      }
      drain_vm();          // stores reached LLC (coherence point)
      __syncthreads();
      if (tid == 0)
        __hip_atomic_store(myflag, (u32)(t + 1), __ATOMIC_RELAXED, __HIP_MEMORY_SCOPE_AGENT);
    }
  } else {
    // ------------- elementwise + LN role, one WG per batch row -------------
    float* red = (float*)smem_raw;
    const int b = bid - 128;
    const int j0 = tid * 2, j1 = tid * 2 + 1;
    float ca0 = c0in[(size_t)b * kH + j0], ca1 = c0in[(size_t)b * kH + j1];
    float cb0 = c0in[(size_t)kB * kH + (size_t)b * kH + j0];
    float cb1 = c0in[(size_t)kB * kH + (size_t)b * kH + j1];

    EwConst K0, K1;
    K0.bi0 = b0[j0]; K0.bf0 = b0[kH + j0]; K0.bo0 = b0[2 * kH + j0]; K0.bc0 = b0[3 * kH + j0];
    K0.bi1 = b0[j1]; K0.bf1 = b0[kH + j1]; K0.bo1 = b0[2 * kH + j1]; K0.bc1 = b0[3 * kH + j1];
    K0.ga0 = lg0[j0]; K0.ga1 = lg0[j1]; K0.be0 = lb0[j0]; K0.be1 = lb0[j1];
    K1.bi0 = b1[j0]; K1.bf0 = b1[kH + j0]; K1.bo0 = b1[2 * kH + j0]; K1.bc0 = b1[3 * kH + j0];
    K1.bi1 = b1[j1]; K1.bf1 = b1[kH + j1]; K1.bo1 = b1[2 * kH + j1]; K1.bc1 = b1[3 * kH + j1];
    K1.ga0 = lg1[j0]; K1.ga1 = lg1[j1]; K1.be0 = lb1[j0]; K1.be1 = lb1[j1];

    for (int tau = 0; tau <= kSeq; ++tau) {
      if (tau < kSeq) {             // layer0, step tau
        if (tid < 64) wait_flags_ge(g0f, (u32)(tau + 1));
        __syncthreads();
        const bool last = (tau == kSeq - 1);
        ew_cell(g0p, K0, ca0, ca1, b, tid,
                hA + (size_t)(tau & 1) * kB * kH + (size_t)b * kH,
                nullptr,
                last ? out + OUT_HFIN + (size_t)b * kH : nullptr,
                last ? out + OUT_CFIN + (size_t)b * kH : nullptr, red);
        drain_vm();
        __syncthreads();
        if (tid == 0)
          __hip_atomic_store(hAf + b, (u32)(tau + 1), __ATOMIC_RELAXED, __HIP_MEMORY_SCOPE_AGENT);
      }
      if (tau >= 1) {               // layer1, step tau-1
        const int t = tau - 1;
        if (tid < 64) wait_flags_ge(g1f, (u32)(t + 1));
        __syncthreads();
        const bool last = (t == kSeq - 1);
        ew_cell(g1p, K1, cb0, cb1, b, tid,
                hB + (size_t)(t & 1) * kB * kH + (size_t)b * kH,
                out + ((size_t)t * kB + b) * kH,
                last ? out + OUT_HFIN + (size_t)kB * kH + (size_t)b * kH : nullptr,
                last ? out + OUT_CFIN + (size_t)kB * kH + (size_t)b * kH : nullptr, red);
        drain_vm();
        __syncthreads();
        if (tid == 0)
          __hip_atomic_store(hBf + b, (u32)(t + 1), __ATOMIC_RELAXED, __HIP_MEMORY_SCOPE_AGENT);
      }
    }
  }
}

// ---------------------------------------------------------------- launch
extern "C" void kernel_launch(void* const* d_in, const int* in_sizes, int n_in,
                              void* d_out, int out_size, void* d_ws, size_t ws_size,
                              hipStream_t stream) {
  (void)in_sizes; (void)n_in; (void)out_size;
  const float* x   = (const float*)d_in[0];
  const float* h0  = (const float*)d_in[1];
  const float* c0  = (const float*)d_in[2];
  const float* W0  = (const float*)d_in[3];
  const float* b0  = (const float*)d_in[4];
  const float* g0  = (const float*)d_in[5];
  const float* be0 = (const float*)d_in[6];
  const float* W1  = (const float*)d_in[7];
  const float* b1  = (const float*)d_in[8];
  const float* g1  = (const float*)d_in[9];
  const float* be1 = (const float*)d_in[10];
  float* out = (float*)d_out;

  if (ws_size < WS_NEED) return;   // fail loudly (output stays poisoned)

  char* w = (char*)d_ws;
  u32* flags = (u32*)(w + OF_FLAGS);
  u16* hA    = (u16*)(w + OF_HA);
  u16* hB    = (u16*)(w + OF_HB);
  float* g0p = (float*)(w + OF_G0P);
  float* g1p = (float*)(w + OF_G1P);
  u16* w0s   = (u16*)(w + OF_W0);
  u16* w1s   = (u16*)(w + OF_W1);
  u16* xbf   = (u16*)(w + OF_XBF);

  hipLaunchKernelGGL(conv_x_k,  dim3(2048), dim3(256), 0, stream, x, xbf, (size_t)kSeq * kB * kIn);
  hipLaunchKernelGGL(conv_w0_k, dim3(6144), dim3(256), 0, stream, W0, w0s);
  hipLaunchKernelGGL(conv_w1_k, dim3(8192), dim3(256), 0, stream, W1, w1s);
  hipLaunchKernelGGL(init_k,    dim3(128),  dim3(256), 0, stream, flags, hA, hB, h0);
  hipLaunchKernelGGL(lstm_persist, dim3(192), dim3(256), 65536, stream,
                     xbf, w0s, w1s, hA, hB, g0p, g1p, flags,
                     b0, g0, be0, b1, g1, be1, c0, out);
}

// Round 4
// 15410.178 us; speedup vs baseline: 3.7815x; 1.1478x over previous
//
#include <hip/hip_runtime.h>

// ----------------------------------------------------------------------------
// 2-layer LayerNorm-LSTM, SEQ=1024, B=64, IN=256, H=512.
// 128 persistent WGs, fixed roles: bid 0..63 = layer-0 team, 64..127 = layer-1
// team. Each WG owns 8 hidden columns (all 4 gates): weights fully LDS-
// resident, fused matmul (bf16 MFMA 16x16x32) + elementwise + LN, cell state
// in registers. Cross-WG data via sc0+sc1 (LLC-coherent) wide asm accesses;
// flags via relaxed agent-scope atomics (round-2-proven). LN via 2-scalar
// per-row stats exchange (32 KB/step) instead of 4 MB/step gate partials.
// ----------------------------------------------------------------------------

typedef short  s16x8 __attribute__((ext_vector_type(8)));
typedef float  f32x4 __attribute__((ext_vector_type(4)));
typedef float  f32x2 __attribute__((ext_vector_type(2)));
typedef unsigned short u16;
typedef unsigned int   u32;

constexpr int kSeq = 1024;

// ws layout (bytes)
constexpr size_t OF_FLAGS = 0;            // u32[256]: HF0[64] HF1[64] PF0[64] PF1[64]
constexpr size_t OF_PART0 = 1024;         // [64 rows][64 wg][2 f32] = 32768
constexpr size_t OF_PART1 = 33792;        // 32768
constexpr size_t OF_HA    = 66560;        // [2 parity][64][512] u16 = 131072
constexpr size_t OF_HB    = 197632;       // 131072
constexpr size_t OF_W0S   = 328704;       // 64*24*1024 u16 = 3145728
constexpr size_t OF_W1S   = 3474432;      // 64*32*1024 u16 = 4194304
constexpr size_t OF_XBF   = 7668736;      // 1024*64*256 u16 = 33554432
constexpr size_t WS_NEED  = OF_XBF + 33554432;

constexpr size_t OUT_HFIN = (size_t)kSeq * 64 * 512;
constexpr size_t OUT_CFIN = OUT_HFIN + 2 * 64 * 512;

__device__ __forceinline__ u16 f2bf(float f) {
  u32 u = __float_as_uint(f);
  return (u16)((u + 0x7fffu + ((u >> 16) & 1u)) >> 16);  // RNE; finite inputs
}

// ---------------- LLC-coherent (sc0 sc1) access helpers ---------------------
__device__ __forceinline__ void ldg16_coh(s16x8& d, const void* p) {
  asm volatile("global_load_dwordx4 %0, %1, off sc0 sc1" : "=v"(d) : "v"(p) : "memory");
}
__device__ __forceinline__ void ldg16f_coh(f32x4& d, const void* p) {
  asm volatile("global_load_dwordx4 %0, %1, off sc0 sc1" : "=v"(d) : "v"(p) : "memory");
}
__device__ __forceinline__ void stg8_coh(float* p, float a, float b) {
  f32x2 t; t[0] = a; t[1] = b;
  asm volatile("global_store_dwordx2 %0, %1, off sc0 sc1" :: "v"(p), "v"(t) : "memory");
}
__device__ __forceinline__ void stg2_coh(u16* p, u32 v) {
  asm volatile("global_store_short %0, %1, off sc0 sc1" :: "v"(p), "v"(v) : "memory");
}
__device__ __forceinline__ void vm_wait() {
  asm volatile("s_waitcnt vmcnt(0)" ::: "memory");
  __builtin_amdgcn_sched_barrier(0);     // rule 18: keep MFMAs below the wait
}
// Spin until all 64 flags[lane] >= tgt. Called by one full wave.
__device__ __forceinline__ void waitge(u32* f, u32 tgt) {
  const int l = threadIdx.x & 63;
  while (true) {
    u32 v = __hip_atomic_load(&f[l], __ATOMIC_RELAXED, __HIP_MEMORY_SCOPE_AGENT);
    if (__all((int)(v >= tgt))) break;
    __builtin_amdgcn_s_sleep(2);
  }
}

// ---------------------------------------------------------------- conversions
__global__ void conv_x_k(const float* __restrict__ x, u16* __restrict__ xd, size_t n) {
  size_t i = (size_t)blockIdx.x * blockDim.x + threadIdx.x;
  size_t st = (size_t)gridDim.x * blockDim.x;
  for (; i < n; i += st) xd[i] = f2bf(x[i]);
}

// W [2048][Kdim] -> [ns(64)][kst(KST)][nt(2)][lane(64)][e(8)]
// lv = nt*16 + (lane&15) in [0,32): gate g = lv>>3, jl = lv&7
// n_orig = g*512 + ns*8 + jl ; k = kst*32 + (lane>>4)*8 + e
__global__ void conv_w_k(const float* __restrict__ W, u16* __restrict__ Wd,
                         int KST, int Kdim) {
  int i = blockIdx.x * blockDim.x + threadIdx.x;
  if (i >= 64 * KST * 1024) return;
  int e = i & 7, lane = (i >> 3) & 63, nt = (i >> 9) & 1;
  int r = i >> 10;
  int kst = r % KST, ns = r / KST;
  int lv = nt * 16 + (lane & 15);
  int n_orig = (lv >> 3) * 512 + ns * 8 + (lv & 7);
  int k = kst * 32 + ((lane >> 4) << 3) + e;
  Wd[i] = f2bf(W[(size_t)n_orig * Kdim + k]);
}

__global__ void init_k(char* ws, const float* __restrict__ h0) {
  int i = blockIdx.x * blockDim.x + threadIdx.x;   // 0..32767
  u32* f = (u32*)ws;
  if (i < 256) f[i] = 0u;
  // parity-1 buffers <- initial hidden states
  ((u16*)(ws + OF_HA))[32768 + i] = f2bf(h0[i]);
  ((u16*)(ws + OF_HB))[32768 + i] = f2bf(h0[32768 + i]);
}

// ---------------------------------------------------------------- team loop
template <int ROLE>
__device__ __forceinline__ void team_loop(
    int ns, char* smem,
    const u16* __restrict__ xbf, const u16* __restrict__ wsw,
    u16* hA, u16* hB, float* part, u32* flags,
    const float* __restrict__ bias, const float* __restrict__ gam_,
    const float* __restrict__ bet_, const float* __restrict__ c0in,
    float* __restrict__ out)
{
  constexpr int KST = ROLE ? 32 : 24;     // K/32
  const int tid = threadIdx.x;
  const int lane = tid & 63, wid = tid >> 6;
  const int arow = wid * 16 + (lane & 15);        // batch row for A-frag
  const int acol = (lane >> 4) << 3;              // K offset within 32
  const int b1r = tid >> 3, jl = tid & 7, b2r = b1r + 32;
  const int jg = ns * 8 + jl;                     // owned hidden column

  u32* HF0 = flags;
  u32* HF1 = flags + 64;
  u32* PF  = flags + 128 + ROLE * 64;
  u32* HF  = ROLE ? HF1 : HF0;

  s16x8* wl    = (s16x8*)smem;                    // KST*128 frags (48/64 KB)
  float* gates = (float*)(smem + 65536);          // [64][32] f32
  float* mus   = (float*)(smem + 73728);          // [64][2]

  // weights fully into LDS
  const u16* wbase = wsw + (size_t)ns * KST * 1024;
  for (int i = tid; i < KST * 128; i += 256)
    wl[i] = *(const s16x8*)(wbase + (size_t)i * 8);

  const float bi = bias[jg], bf_ = bias[512 + jg], bo = bias[1024 + jg], bc = bias[1536 + jg];
  const float gm = gam_[jg], bt = bet_[jg];
  float cA = c0in[(size_t)(ROLE * 64 + b1r) * 512 + jg];
  float cB = c0in[(size_t)(ROLE * 64 + b2r) * 512 + jg];
  __syncthreads();

  for (int t = 0; t < kSeq; ++t) {
    f32x4 acc0 = {0.f, 0.f, 0.f, 0.f}, acc1 = {0.f, 0.f, 0.f, 0.f};

    auto mm = [&](s16x8 av, int kst) {
      acc0 = __builtin_amdgcn_mfma_f32_16x16x32_bf16(av, wl[(kst * 2) * 64 + lane], acc0, 0, 0, 0);
      acc1 = __builtin_amdgcn_mfma_f32_16x16x32_bf16(av, wl[(kst * 2 + 1) * 64 + lane], acc1, 0, 0, 0);
    };

    if (ROLE == 0) {
      // x prefetch (static, cached) before the flag wait
      s16x8 xp[8];
      const u16* xrow = xbf + ((size_t)t * 64 + arow) * 256 + acol;
      #pragma unroll
      for (int kk = 0; kk < 8; ++kk) xp[kk] = *(const s16x8*)(xrow + kk * 32);
      if (wid == 0)      { if (t > 0)  waitge(HF0, (u32)t); }        // h(t-1) ready + part safety
      else if (wid == 1) { if (t >= 2) waitge(HF1, (u32)(t - 1)); }  // hA overwrite backpressure
      __syncthreads();
      s16x8 a[16];
      const u16* hrow = hA + (size_t)((t + 1) & 1) * 32768 + (size_t)arow * 512 + acol;
      #pragma unroll
      for (int kk = 0; kk < 16; ++kk) ldg16_coh(a[kk], hrow + kk * 32);
      #pragma unroll
      for (int kk = 0; kk < 8; ++kk) mm(xp[kk], kk);                 // overlap with h loads
      vm_wait();
      #pragma unroll
      for (int kk = 0; kk < 16; ++kk) mm(a[kk], 8 + kk);
    } else {
      // phase A: own-team hB(t-1) (usually no wait)
      if (wid == 1) { if (t > 0) waitge(HF1, (u32)t); }
      __syncthreads();
      s16x8 a[16];
      const u16* hbrow = hB + (size_t)((t + 1) & 1) * 32768 + (size_t)arow * 512 + acol;
      #pragma unroll
      for (int kk = 0; kk < 16; ++kk) ldg16_coh(a[kk], hbrow + kk * 32);
      vm_wait();
      #pragma unroll
      for (int kk = 0; kk < 16; ++kk) mm(a[kk], 16 + kk);
      // phase B: fresh hA(t) from layer 0
      if (wid == 0) waitge(HF0, (u32)(t + 1));
      __syncthreads();
      const u16* harow = hA + (size_t)(t & 1) * 32768 + (size_t)arow * 512 + acol;
      #pragma unroll
      for (int kk = 0; kk < 16; ++kk) ldg16_coh(a[kk], harow + kk * 32);
      vm_wait();
      #pragma unroll
      for (int kk = 0; kk < 16; ++kk) mm(a[kk], kk);
    }

    // D layout: col = lane&15 (lv), row = (lane>>4)*4 + r (batch)  [m89]
    #pragma unroll
    for (int r = 0; r < 4; ++r) {
      const int b = wid * 16 + ((lane >> 4) << 2) + r;
      gates[b * 32 + (lane & 15)]      = acc0[r];
      gates[b * 32 + 16 + (lane & 15)] = acc1[r];
    }
    __syncthreads();

    // ---------------- elementwise + distributed LN
    const float giA = gates[b1r * 32 + jl] + bi;
    const float gfA = gates[b1r * 32 + 8 + jl] + bf_;
    const float goA = gates[b1r * 32 + 16 + jl] + bo;
    const float gcA = gates[b1r * 32 + 24 + jl] + bc;
    const float giB = gates[b2r * 32 + jl] + bi;
    const float gfB = gates[b2r * 32 + 8 + jl] + bf_;
    const float goB = gates[b2r * 32 + 16 + jl] + bo;
    const float gcB = gates[b2r * 32 + 24 + jl] + bc;
    const float iA = 1.f / (1.f + __expf(-giA));
    const float fA = 1.f / (1.f + __expf(-gfA));
    const float oA = 1.f / (1.f + __expf(-goA));
    const float iB = 1.f / (1.f + __expf(-giB));
    const float fB = 1.f / (1.f + __expf(-gfB));
    const float oB = 1.f / (1.f + __expf(-goB));
    const float cnA = iA * tanhf(gcA) + fA * cA;
    const float cnB = iB * tanhf(gcB) + fB * cB;
    cA = cnA; cB = cnB;

    float s1 = cnA, q1 = cnA * cnA, s2 = cnB, q2 = cnB * cnB;
    #pragma unroll
    for (int m = 1; m <= 4; m <<= 1) {
      s1 += __shfl_xor(s1, m); q1 += __shfl_xor(q1, m);
      s2 += __shfl_xor(s2, m); q2 += __shfl_xor(q2, m);
    }
    if (jl == 0) {
      stg8_coh(part + ((size_t)b1r * 64 + ns) * 2, s1, q1);
      stg8_coh(part + ((size_t)b2r * 64 + ns) * 2, s2, q2);
    }
    vm_wait();
    __syncthreads();
    if (tid == 0)
      __hip_atomic_store(&PF[ns], (u32)(t + 1), __ATOMIC_RELAXED, __HIP_MEMORY_SCOPE_AGENT);
    if (wid == 0) waitge(PF, (u32)(t + 1));
    __syncthreads();
    if (tid < 64) {
      float ssum = 0.f, qsum = 0.f;
      const float* pr = part + (size_t)tid * 128;
      #pragma unroll
      for (int bch = 0; bch < 4; ++bch) {
        f32x4 gb[8];
        #pragma unroll
        for (int i2 = 0; i2 < 8; ++i2) ldg16f_coh(gb[i2], pr + (bch * 8 + i2) * 4);
        vm_wait();
        #pragma unroll
        for (int i2 = 0; i2 < 8; ++i2) { ssum += gb[i2][0] + gb[i2][2]; qsum += gb[i2][1] + gb[i2][3]; }
      }
      const float mu = ssum * (1.f / 512.f);
      const float ms = qsum * (1.f / 512.f);
      mus[tid * 2]     = mu;
      mus[tid * 2 + 1] = rsqrtf(ms - mu * mu + 1e-5f);
    }
    __syncthreads();
    const float muA = mus[b1r * 2], rsA = mus[b1r * 2 + 1];
    const float muB = mus[b2r * 2], rsB = mus[b2r * 2 + 1];
    const float hvA = oA * tanhf((cnA - muA) * rsA * gm + bt);
    const float hvB = oB * tanhf((cnB - muB) * rsB * gm + bt);
    const u32 ha16 = f2bf(hvA), hb16 = f2bf(hvB);

    u16* hd = (ROLE ? hB : hA) + (size_t)(t & 1) * 32768;
    stg2_coh(hd + (size_t)b1r * 512 + jg, ha16);
    stg2_coh(hd + (size_t)b2r * 512 + jg, hb16);
    if (ROLE == 1) {
      out[((size_t)t * 64 + b1r) * 512 + jg] = hvA;
      out[((size_t)t * 64 + b2r) * 512 + jg] = hvB;
    }
    if (t == kSeq - 1) {
      const size_t hb_ = OUT_HFIN + (size_t)ROLE * 32768;
      const size_t cb_ = OUT_CFIN + (size_t)ROLE * 32768;
      out[hb_ + (size_t)b1r * 512 + jg] = hvA;
      out[hb_ + (size_t)b2r * 512 + jg] = hvB;
      out[cb_ + (size_t)b1r * 512 + jg] = cnA;
      out[cb_ + (size_t)b2r * 512 + jg] = cnB;
    }
    vm_wait();
    __syncthreads();
    if (tid == 0)
      __hip_atomic_store(&HF[ns], (u32)(t + 1), __ATOMIC_RELAXED, __HIP_MEMORY_SCOPE_AGENT);
  }
}

// ---------------------------------------------------------------- persistent
__global__ __launch_bounds__(256, 1) void lstm_persist(
    const u16* __restrict__ xbf, const u16* __restrict__ w0s, const u16* __restrict__ w1s,
    char* ws,
    const float* __restrict__ b0, const float* __restrict__ lg0, const float* __restrict__ lb0,
    const float* __restrict__ b1, const float* __restrict__ lg1, const float* __restrict__ lb1,
    const float* __restrict__ c0in, float* __restrict__ out)
{
  extern __shared__ char smem[];
  const int bid = blockIdx.x;
  u32*   flags = (u32*)(ws + OF_FLAGS);
  u16*   hA    = (u16*)(ws + OF_HA);
  u16*   hB    = (u16*)(ws + OF_HB);
  float* p0    = (float*)(ws + OF_PART0);
  float* p1    = (float*)(ws + OF_PART1);

  if (bid < 64)
    team_loop<0>(bid, smem, xbf, w0s, hA, hB, p0, flags, b0, lg0, lb0, c0in, out);
  else
    team_loop<1>(bid - 64, smem, xbf, w1s, hA, hB, p1, flags, b1, lg1, lb1, c0in, out);
}

// ---------------------------------------------------------------- launch
extern "C" void kernel_launch(void* const* d_in, const int* in_sizes, int n_in,
                              void* d_out, int out_size, void* d_ws, size_t ws_size,
                              hipStream_t stream) {
  (void)in_sizes; (void)n_in; (void)out_size;
  const float* x   = (const float*)d_in[0];
  const float* h0  = (const float*)d_in[1];
  const float* c0  = (const float*)d_in[2];
  const float* W0  = (const float*)d_in[3];
  const float* b0  = (const float*)d_in[4];
  const float* g0  = (const float*)d_in[5];
  const float* be0 = (const float*)d_in[6];
  const float* W1  = (const float*)d_in[7];
  const float* b1  = (const float*)d_in[8];
  const float* g1  = (const float*)d_in[9];
  const float* be1 = (const float*)d_in[10];
  float* out = (float*)d_out;

  if (ws_size < WS_NEED) return;   // fail loudly (output stays poisoned)

  char* ws = (char*)d_ws;
  u16* w0s = (u16*)(ws + OF_W0S);
  u16* w1s = (u16*)(ws + OF_W1S);
  u16* xbf = (u16*)(ws + OF_XBF);

  hipLaunchKernelGGL(conv_x_k, dim3(2048), dim3(256), 0, stream,
                     x, xbf, (size_t)kSeq * 64 * 256);
  hipLaunchKernelGGL(conv_w_k, dim3(6144), dim3(256), 0, stream, W0, w0s, 24, 768);
  hipLaunchKernelGGL(conv_w_k, dim3(8192), dim3(256), 0, stream, W1, w1s, 32, 1024);
  hipLaunchKernelGGL(init_k,   dim3(128),  dim3(256), 0, stream, ws, h0);
  hipLaunchKernelGGL(lstm_persist, dim3(128), dim3(256), 74240, stream,
                     xbf, w0s, w1s, ws,
                     b0, g0, be0, b1, g1, be1, c0, out);
}